// Round 1
// baseline (358.484 us; speedup 1.0000x reference)
//
#include <hip/hip_runtime.h>

typedef __attribute__((ext_vector_type(8))) short short8;
typedef __attribute__((ext_vector_type(4))) float f32x4;
typedef unsigned short u16;

#define B_ 4
#define L_ 2048
#define D_ 1024
#define H_ 16
#define HD_ 64

__device__ __forceinline__ void load_lds16(const void* g, void* l) {
  __builtin_amdgcn_global_load_lds(
      (__attribute__((address_space(1))) unsigned int*)(g),
      (__attribute__((address_space(3))) unsigned int*)(l),
      16, 0, 0);
}

__device__ __forceinline__ u16 f2bf(float f) {
  union { float f; unsigned u; } c; c.f = f;
  unsigned r = c.u + 0x7FFFu + ((c.u >> 16) & 1u);
  return (u16)(r >> 16);
}

// ---------------- f32 -> bf16 conversion (4 elems/thread) ----------------
__global__ __launch_bounds__(256) void cvt_bf16(const float* __restrict__ in,
                                                u16* __restrict__ out, int n) {
  int i = (blockIdx.x * 256 + threadIdx.x) * 4;
  if (i >= n) return;
  float4 v = *(const float4*)(in + i);
  u16 o0 = f2bf(v.x), o1 = f2bf(v.y), o2 = f2bf(v.z), o3 = f2bf(v.w);
  u16* p = out + i;
  p[0] = o0; p[1] = o1; p[2] = o2; p[3] = o3;
}

// ---------------- bf16 GEMM, C = A * B^T + bias (m97 structure) ----------
// A: [M][K] bf16 row-major.  B: [N][K] bf16 row-major (i.e. B^T input).
// 128x128 tile, 4 waves, BK=32, 16x16x32 MFMA, global_load_lds width 16.
template <bool BF16_OUT>
__global__ __launch_bounds__(256, 2) void gemm_bt(
    const u16* __restrict__ A, const u16* __restrict__ B,
    const float* __restrict__ bias, void* __restrict__ Cout,
    int M, int N, int K) {
  __shared__ u16 Asm[128 * 32];
  __shared__ u16 Bsm[128 * 32];
  const int tid = threadIdx.x;
  const int lane = tid & 63;
  const int wid = tid >> 6;
  const int fr = lane & 15, fq = lane >> 4;
  const int wr = wid >> 1, wc = wid & 1;
  const long m0 = (long)blockIdx.y * 128;
  const long n0 = (long)blockIdx.x * 128;
  const int srow = lane >> 2;           // staging row within 16-row section
  const int scol = (lane & 3) * 8;      // staging k-offset (elements)

  f32x4 acc[4][4] = {};

  for (int kt = 0; kt < K; kt += 32) {
    __syncthreads();
#pragma unroll
    for (int c = 0; c < 2; ++c) {
      const int sec = wid * 2 + c;
      load_lds16(A + (m0 + sec * 16 + srow) * K + kt + scol,
                 (char*)Asm + sec * 1024);
      load_lds16(B + (n0 + sec * 16 + srow) * K + kt + scol,
                 (char*)Bsm + sec * 1024);
    }
    __syncthreads();
    short8 af[4], bfr[4];
#pragma unroll
    for (int m = 0; m < 4; ++m)
      af[m] = *(const short8*)((const char*)Asm + (wr * 64 + m * 16 + fr) * 64 + fq * 16);
#pragma unroll
    for (int n = 0; n < 4; ++n)
      bfr[n] = *(const short8*)((const char*)Bsm + (wc * 64 + n * 16 + fr) * 64 + fq * 16);
#pragma unroll
    for (int m = 0; m < 4; ++m)
#pragma unroll
      for (int n = 0; n < 4; ++n)
        acc[m][n] = __builtin_amdgcn_mfma_f32_16x16x32_bf16(af[m], bfr[n], acc[m][n], 0, 0, 0);
  }

  float bv[4];
#pragma unroll
  for (int n = 0; n < 4; ++n) bv[n] = bias[n0 + wc * 64 + n * 16 + fr];

#pragma unroll
  for (int m = 0; m < 4; ++m) {
#pragma unroll
    for (int n = 0; n < 4; ++n) {
      const long col = n0 + wc * 64 + n * 16 + fr;
#pragma unroll
      for (int r = 0; r < 4; ++r) {
        const long row = m0 + wr * 64 + m * 16 + fq * 4 + r;
        float v = acc[m][n][r] + bv[n];
        if (BF16_OUT)
          ((u16*)Cout)[row * N + col] = f2bf(v);
        else
          ((float*)Cout)[row * N + col] = v;
      }
    }
  }
}

// ---------------- causal flash attention ----------------
// qkv: [B*L][3072] bf16 (Q|K|V each 1024, head h at h*64).
// attn out: [B*L][1024] bf16.
// Block: 4 waves, QBLK=64 (16 q-rows/wave), KVBLK=64.
__global__ __launch_bounds__(256, 2) void flash_attn(
    const u16* __restrict__ qkv, u16* __restrict__ attn) {
  __shared__ u16 Klds[64 * 64];      // [kv][d], 16B-chunk XOR-swizzled by (kv&7)
  __shared__ u16 Vt[64 * 72];        // [d][kv], padded rows (144B)
  __shared__ u16 Plds[4 * 16 * 72];  // per-wave [16][72], padded

  const int tid = threadIdx.x;
  const int lane = tid & 63;
  const int wid = tid >> 6;
  const int fr = lane & 15, fq = lane >> 4;
  const int qt = blockIdx.x;             // q tile 0..31
  const int bh = blockIdx.y;             // b*16 + h
  const long rowbase = (long)(bh >> 4) * L_;
  const int h = bh & 15;

  // Q fragments in registers for the whole block
  const long qrow = rowbase + qt * 64 + wid * 16 + fr;
  short8 aq[2];
#pragma unroll
  for (int kk = 0; kk < 2; ++kk)
    aq[kk] = *(const short8*)(qkv + qrow * 3072 + h * 64 + kk * 32 + fq * 8);

  f32x4 o[4] = {};
  float m_r[4], l_r[4];
#pragma unroll
  for (int r = 0; r < 4; ++r) { m_r[r] = -__builtin_inff(); l_r[r] = 0.f; }

  u16* Pw = Plds + wid * (16 * 72);

  for (int kt = 0; kt <= qt; ++kt) {
    __syncthreads();
    // stage K tile (swizzled dest layout via pre-swizzled global source)
#pragma unroll
    for (int c = 0; c < 2; ++c) {
      const int sec = wid * 2 + c;
      const int kr = sec * 8 + (lane >> 3);
      const int src_chunk = (lane & 7) ^ (lane >> 3);
      load_lds16(qkv + (rowbase + kt * 64 + kr) * 3072 + 1024 + h * 64 + src_chunk * 8,
                 (char*)Klds + sec * 1024);
    }
    // stage V transposed: thread t -> kv=t/4, d0=(t%4)*16
    {
      const int kv = tid >> 2;
      const int d0 = (tid & 3) * 16;
      const u16* g = qkv + (rowbase + kt * 64 + kv) * 3072 + 2048 + h * 64 + d0;
      short8 v0 = *(const short8*)g;
      short8 v1 = *(const short8*)(g + 8);
#pragma unroll
      for (int j = 0; j < 8; ++j) {
        Vt[(d0 + j) * 72 + kv] = (u16)v0[j];
        Vt[(d0 + 8 + j) * 72 + kv] = (u16)v1[j];
      }
    }
    __syncthreads();

    // S = Q K^T  (per wave: 16 x 64)
    f32x4 s[4] = {};
#pragma unroll
    for (int f = 0; f < 4; ++f) {
      const int kr = f * 16 + fr;
#pragma unroll
      for (int kk = 0; kk < 2; ++kk) {
        const int chunk = (kk * 4 + fq) ^ (kr & 7);
        short8 bk = *(const short8*)((const char*)Klds + kr * 128 + chunk * 16);
        s[f] = __builtin_amdgcn_mfma_f32_16x16x32_bf16(aq[kk], bk, s[f], 0, 0, 0);
      }
    }

    // scale + causal mask (only the diagonal tile is partial)
#pragma unroll
    for (int f = 0; f < 4; ++f)
#pragma unroll
      for (int r = 0; r < 4; ++r) s[f][r] *= 0.125f;
    if (kt == qt) {
#pragma unroll
      for (int f = 0; f < 4; ++f) {
        const int j = f * 16 + fr;
#pragma unroll
        for (int r = 0; r < 4; ++r) {
          const int i = wid * 16 + fq * 4 + r;
          if (j > i) s[f][r] = -__builtin_inff();
        }
      }
    }

    // online softmax (row r lives on reg r of 16-lane group fq)
    float mt[4];
#pragma unroll
    for (int r = 0; r < 4; ++r)
      mt[r] = fmaxf(fmaxf(s[0][r], s[1][r]), fmaxf(s[2][r], s[3][r]));
#pragma unroll
    for (int msk = 1; msk < 16; msk <<= 1)
#pragma unroll
      for (int r = 0; r < 4; ++r) mt[r] = fmaxf(mt[r], __shfl_xor(mt[r], msk));

    float alpha[4];
#pragma unroll
    for (int r = 0; r < 4; ++r) {
      const float mn = fmaxf(m_r[r], mt[r]);
      alpha[r] = __expf(m_r[r] - mn);
      m_r[r] = mn;
    }
#pragma unroll
    for (int f = 0; f < 4; ++f)
#pragma unroll
      for (int r = 0; r < 4; ++r) s[f][r] = __expf(s[f][r] - m_r[r]);

    float rs[4];
#pragma unroll
    for (int r = 0; r < 4; ++r) rs[r] = (s[0][r] + s[1][r]) + (s[2][r] + s[3][r]);
#pragma unroll
    for (int msk = 1; msk < 16; msk <<= 1)
#pragma unroll
      for (int r = 0; r < 4; ++r) rs[r] += __shfl_xor(rs[r], msk);

#pragma unroll
    for (int r = 0; r < 4; ++r) l_r[r] = alpha[r] * l_r[r] + rs[r];
#pragma unroll
    for (int dt = 0; dt < 4; ++dt)
#pragma unroll
      for (int r = 0; r < 4; ++r) o[dt][r] *= alpha[r];

    // P -> LDS (bf16)
#pragma unroll
    for (int f = 0; f < 4; ++f)
#pragma unroll
      for (int r = 0; r < 4; ++r)
        Pw[(fq * 4 + r) * 72 + f * 16 + fr] = f2bf(s[f][r]);

    // O += P V
    short8 ap[2];
#pragma unroll
    for (int kk = 0; kk < 2; ++kk)
      ap[kk] = *(const short8*)((const char*)Pw + fr * 144 + kk * 64 + fq * 16);
#pragma unroll
    for (int dt = 0; dt < 4; ++dt) {
#pragma unroll
      for (int kk = 0; kk < 2; ++kk) {
        short8 bvv = *(const short8*)((const char*)Vt + (dt * 16 + fr) * 144 + kk * 64 + fq * 16);
        o[dt] = __builtin_amdgcn_mfma_f32_16x16x32_bf16(ap[kk], bvv, o[dt], 0, 0, 0);
      }
    }
  }

  // epilogue: normalize and store bf16
#pragma unroll
  for (int dt = 0; dt < 4; ++dt) {
#pragma unroll
    for (int r = 0; r < 4; ++r) {
      const long row = rowbase + qt * 64 + wid * 16 + fq * 4 + r;
      attn[row * 1024 + h * 64 + dt * 16 + fr] = f2bf(o[dt][r] / l_r[r]);
    }
  }
}

extern "C" void kernel_launch(void* const* d_in, const int* in_sizes, int n_in,
                              void* d_out, int out_size, void* d_ws, size_t ws_size,
                              hipStream_t stream) {
  const float* x    = (const float*)d_in[0];
  // d_in[1] = mask: known causal (~tril), handled analytically in flash_attn
  const float* Wqkv = (const float*)d_in[2];
  const float* bqkv = (const float*)d_in[3];
  const float* Wo   = (const float*)d_in[4];
  const float* bo   = (const float*)d_in[5];
  float* out = (float*)d_out;

  const long ML = (long)B_ * L_;  // 8192
  u16* xb    = (u16*)d_ws;                       // [8192][1024]
  u16* wqkvb = xb + ML * D_;                     // [3072][1024]
  u16* wob   = wqkvb + (long)3 * D_ * D_;        // [1024][1024]
  u16* qkv   = wob + (long)D_ * D_;              // [8192][3072]
  u16* attn  = qkv + ML * 3 * D_;                // [8192][1024]

  cvt_bf16<<<dim3((int)(ML * D_ / 1024)), 256, 0, stream>>>(x, xb, (int)(ML * D_));
  cvt_bf16<<<dim3(3 * D_ * D_ / 1024), 256, 0, stream>>>(Wqkv, wqkvb, 3 * D_ * D_);
  cvt_bf16<<<dim3(D_ * D_ / 1024), 256, 0, stream>>>(Wo, wob, D_ * D_);

  gemm_bt<true><<<dim3(3 * D_ / 128, (int)(ML / 128)), 256, 0, stream>>>(
      xb, wqkvb, bqkv, qkv, (int)ML, 3 * D_, D_);

  flash_attn<<<dim3(L_ / 64, B_ * H_), 256, 0, stream>>>(qkv, attn);

  gemm_bt<false><<<dim3(D_ / 128, (int)(ML / 128)), 256, 0, stream>>>(
      attn, wob, bo, out, (int)ML, D_, D_);
}

// Round 3
// 248.897 us; speedup vs baseline: 1.4403x; 1.4403x over previous
//
#include <hip/hip_runtime.h>

typedef __attribute__((ext_vector_type(8))) short short8;
typedef __attribute__((ext_vector_type(4))) float f32x4;
typedef __attribute__((ext_vector_type(16))) float f32x16;
typedef __attribute__((ext_vector_type(2))) int int2v;
typedef __attribute__((ext_vector_type(4))) int int4v;
typedef unsigned short u16;
typedef unsigned int u32;

#define B_ 4
#define L_ 2048
#define D_ 1024
#define H_ 16
#define HD_ 64

__device__ __forceinline__ void load_lds16(const void* g, void* l) {
  __builtin_amdgcn_global_load_lds(
      (__attribute__((address_space(1))) unsigned int*)(g),
      (__attribute__((address_space(3))) unsigned int*)(l),
      16, 0, 0);
}

__device__ __forceinline__ u16 f2bf(float f) {
  union { float f; unsigned u; } c; c.f = f;
  unsigned r = c.u + 0x7FFFu + ((c.u >> 16) & 1u);
  return (u16)(r >> 16);
}

__device__ __forceinline__ u32 cvtpk(float a, float b) {
  u32 r; asm("v_cvt_pk_bf16_f32 %0, %1, %2" : "=v"(r) : "v"(a), "v"(b)); return r;
}

__device__ __forceinline__ int2v trread(u32 addr) {
  int2v r; asm volatile("ds_read_b64_tr_b16 %0, %1" : "=v"(r) : "v"(addr)); return r;
}

// ---------------- f32 -> bf16 conversion (4 elems/thread) ----------------
__global__ __launch_bounds__(256) void cvt_bf16(const float* __restrict__ in,
                                                u16* __restrict__ out, int n) {
  int i = (blockIdx.x * 256 + threadIdx.x) * 4;
  if (i >= n) return;
  float4 v = *(const float4*)(in + i);
  u16 o0 = f2bf(v.x), o1 = f2bf(v.y), o2 = f2bf(v.z), o3 = f2bf(v.w);
  u16* p = out + i;
  p[0] = o0; p[1] = o1; p[2] = o2; p[3] = o3;
}

// ---------------- bf16 GEMM, C = A * B^T + bias (m97 structure) ----------
template <bool BF16_OUT>
__global__ __launch_bounds__(256, 2) void gemm_bt(
    const u16* __restrict__ A, const u16* __restrict__ B,
    const float* __restrict__ bias, void* __restrict__ Cout,
    int M, int N, int K) {
  __shared__ u16 Asm[128 * 32];
  __shared__ u16 Bsm[128 * 32];
  const int tid = threadIdx.x;
  const int lane = tid & 63;
  const int wid = tid >> 6;
  const int fr = lane & 15, fq = lane >> 4;
  const int wr = wid >> 1, wc = wid & 1;
  const long m0 = (long)blockIdx.y * 128;
  const long n0 = (long)blockIdx.x * 128;
  const int srow = lane >> 2;
  const int scol = (lane & 3) * 8;

  f32x4 acc[4][4] = {};

  for (int kt = 0; kt < K; kt += 32) {
    __syncthreads();
#pragma unroll
    for (int c = 0; c < 2; ++c) {
      const int sec = wid * 2 + c;
      load_lds16(A + (m0 + sec * 16 + srow) * K + kt + scol,
                 (char*)Asm + sec * 1024);
      load_lds16(B + (n0 + sec * 16 + srow) * K + kt + scol,
                 (char*)Bsm + sec * 1024);
    }
    __syncthreads();
    short8 af[4], bfr[4];
#pragma unroll
    for (int m = 0; m < 4; ++m)
      af[m] = *(const short8*)((const char*)Asm + (wr * 64 + m * 16 + fr) * 64 + fq * 16);
#pragma unroll
    for (int n = 0; n < 4; ++n)
      bfr[n] = *(const short8*)((const char*)Bsm + (wc * 64 + n * 16 + fr) * 64 + fq * 16);
#pragma unroll
    for (int m = 0; m < 4; ++m)
#pragma unroll
      for (int n = 0; n < 4; ++n)
        acc[m][n] = __builtin_amdgcn_mfma_f32_16x16x32_bf16(af[m], bfr[n], acc[m][n], 0, 0, 0);
  }

  float bv[4];
#pragma unroll
  for (int n = 0; n < 4; ++n) bv[n] = bias[n0 + wc * 64 + n * 16 + fr];

#pragma unroll
  for (int m = 0; m < 4; ++m) {
#pragma unroll
    for (int n = 0; n < 4; ++n) {
      const long col = n0 + wc * 64 + n * 16 + fr;
#pragma unroll
      for (int r = 0; r < 4; ++r) {
        const long row = m0 + wr * 64 + m * 16 + fq * 4 + r;
        float v = acc[m][n][r] + bv[n];
        if (BF16_OUT)
          ((u16*)Cout)[row * N + col] = f2bf(v);
        else
          ((float*)Cout)[row * N + col] = v;
      }
    }
  }
}

// ---------------- causal flash attention v2 (swapped-operand, 32x32) -----
// qkv: [B*L][3072] bf16 (Q|K|V each 1024, head hh at hh*64).
// Block: 4 waves x 32 q-rows = 128 q-rows. KV tile = 64.
// S^T = mfma(A=K, B=Q): lane q = lane&31, kv in regs -> lane-local softmax.
// O^T = mfma(A=V^T (tr-reads), B=P^T (cvt_pk+shfl pack)).
__global__ __launch_bounds__(256, 3) void flash_attn2(
    const u16* __restrict__ qkv, u16* __restrict__ attn) {
  __shared__ u16 Klds[64 * 64];  // [row][chunk^ (row&7)] 16B-chunk swizzled
  __shared__ u16 Vlds[64 * 64];  // subtiled [kv/4][d/16][4][16]

  const int tid = threadIdx.x;
  const int lane = tid & 63;
  const int wid = tid >> 6;
  const int l31 = lane & 31;
  const int h = lane >> 5;               // k-half
  const int qt = 15 - blockIdx.x;        // descending: heavy tiles first
  const int bh = blockIdx.y;
  const long rowbase = (long)(bh >> 4) * L_;
  const int hh = bh & 15;
  const int wq0 = qt * 128 + wid * 32;
  const int wq_last = wq0 + 31;
  const int q_glob = wq0 + l31;

  // Q fragments in registers: B[k=hd][n=q]; lane holds Q[q_glob][ks*16+h*8+j]
  short8 qf[4];
  {
    const u16* qptr = qkv + (rowbase + q_glob) * 3072 + hh * 64 + h * 8;
#pragma unroll
    for (int ks = 0; ks < 4; ++ks) qf[ks] = *(const short8*)(qptr + ks * 16);
  }

  // staging lane->global mapping (per wave inst c=0,1)
  const int i = lane;
  int krow[2], kvv[2], dvv[2];
#pragma unroll
  for (int c = 0; c < 2; ++c) {
    const int sec = wid * 2 + c;
    const int s = sec * 8 + (i >> 3);
    krow[c] = s;
    kvv[c] = ((s >> 2) << 2) + ((i >> 1) & 3);
    dvv[c] = ((s & 3) << 4) + ((i & 1) << 3);
  }
  const int kchunk = ((i & 7) ^ (i >> 3)) * 8;

  // tr-read base address (bytes into Vlds)
  const u32 Vaddr = (u32)(unsigned long long)(__attribute__((address_space(3))) char*)(void*)Vlds;
  const u32 vb = Vaddr + ((lane >> 4) & 1) * 128 + (lane & 15) * 8 + h * 1024;

  f32x16 o[2] = {};
  float m_r = -__builtin_inff(), l_r = 0.f;
  const float SC2 = 0.125f * 1.4426950408889634f;  // scale * log2(e)

  const int ktmax = 2 * qt + 1;
  for (int kt = 0; kt <= ktmax; ++kt) {
    const int ktb = kt * 64;
    __syncthreads();
#pragma unroll
    for (int c = 0; c < 2; ++c) {
      load_lds16(qkv + (rowbase + ktb + krow[c]) * 3072 + 1024 + hh * 64 + kchunk,
                 (char*)Klds + (wid * 2 + c) * 1024);
      load_lds16(qkv + (rowbase + ktb + kvv[c]) * 3072 + 2048 + hh * 64 + dvv[c],
                 (char*)Vlds + (wid * 2 + c) * 1024);
    }
    __syncthreads();
    if (ktb > wq_last) continue;  // fully-masked for this wave (barriers done)

    // S^T = K * Q^T  -> p[t]: lane holds q=l31, kv = ktb + t*32 + (r&3)+8*(r>>2)+4*h
    f32x16 p[2];
#pragma unroll
    for (int t = 0; t < 2; ++t) {
      f32x16 acc = {};
#pragma unroll
      for (int ks = 0; ks < 4; ++ks) {
        const int row = t * 32 + l31;
        short8 kf = *(const short8*)((const char*)Klds + row * 128 +
                                     (((ks * 2 + h) ^ (row & 7)) * 16));
        acc = __builtin_amdgcn_mfma_f32_32x32x16_bf16(kf, qf[ks], acc, 0, 0, 0);
      }
      p[t] = acc;
    }

    // causal mask: needed whenever the tile can reach past the wave's FIRST q row
    if (ktb + 63 > wq0) {
#pragma unroll
      for (int t = 0; t < 2; ++t)
#pragma unroll
        for (int r = 0; r < 16; ++r) {
          const int kvg = ktb + t * 32 + (r & 3) + 8 * (r >> 2) + 4 * h;
          p[t][r] = (kvg > q_glob) ? -__builtin_inff() : p[t][r];
        }
    }

    // row max: register tree + one cross-half exchange
    float a[16];
#pragma unroll
    for (int r = 0; r < 16; ++r) a[r] = fmaxf(p[0][r], p[1][r]);
#pragma unroll
    for (int s = 8; s > 0; s >>= 1)
#pragma unroll
      for (int r = 0; r < s; ++r) a[r] = fmaxf(a[r], a[r + s]);
    const float mt = fmaxf(a[0], __shfl_xor(a[0], 32));

    const float m_new = fmaxf(m_r, mt);
    const float alpha = __builtin_exp2f((m_r - m_new) * SC2);
    const float msc = m_new * SC2;
#pragma unroll
    for (int t = 0; t < 2; ++t)
#pragma unroll
      for (int r = 0; r < 16; ++r)
        p[t][r] = __builtin_exp2f(fmaf(p[t][r], SC2, -msc));

    // row sum
    float b2[16];
#pragma unroll
    for (int r = 0; r < 16; ++r) b2[r] = p[0][r] + p[1][r];
#pragma unroll
    for (int s = 8; s > 0; s >>= 1)
#pragma unroll
      for (int r = 0; r < s; ++r) b2[r] += b2[r + s];
    const float rs = b2[0] + __shfl_xor(b2[0], 32);

    l_r = alpha * l_r + rs;
    m_r = m_new;
#pragma unroll
    for (int t = 0; t < 2; ++t)
#pragma unroll
      for (int r = 0; r < 16; ++r) o[t][r] *= alpha;

    // pack P^T fragments: frag ks covers kv [16ks,16ks+16); lane needs kv=16ks+8h+j
    u32 pf[4][4];
#pragma unroll
    for (int t = 0; t < 2; ++t)
#pragma unroll
      for (int ksl = 0; ksl < 2; ++ksl) {
        const u32 x0 = cvtpk(p[t][8 * ksl + 0], p[t][8 * ksl + 1]);
        const u32 x1 = cvtpk(p[t][8 * ksl + 2], p[t][8 * ksl + 3]);
        const u32 y0 = cvtpk(p[t][8 * ksl + 4], p[t][8 * ksl + 5]);
        const u32 y1 = cvtpk(p[t][8 * ksl + 6], p[t][8 * ksl + 7]);
        const u32 r0 = (u32)__shfl_xor((int)(h ? x0 : y0), 32);
        const u32 r1 = (u32)__shfl_xor((int)(h ? x1 : y1), 32);
        const int ks = t * 2 + ksl;
        pf[ks][0] = h ? r0 : x0;
        pf[ks][1] = h ? r1 : x1;
        pf[ks][2] = h ? y0 : r0;
        pf[ks][3] = h ? y1 : r1;
      }

    // O^T += V^T * P^T ; V^T frags via ds_read_b64_tr_b16 on subtiled Vlds
#pragma unroll
    for (int dt = 0; dt < 2; ++dt) {
      int2v vf[8];
#pragma unroll
      for (int ks = 0; ks < 4; ++ks) {
        vf[ks * 2 + 0] = trread(vb + dt * 256 + ks * 2048);
        vf[ks * 2 + 1] = trread(vb + dt * 256 + ks * 2048 + 512);
      }
      asm volatile("s_waitcnt lgkmcnt(0)" ::: "memory");
      __builtin_amdgcn_sched_barrier(0);
#pragma unroll
      for (int ks = 0; ks < 4; ++ks) {
        int4v av;
        av[0] = vf[ks * 2][0]; av[1] = vf[ks * 2][1];
        av[2] = vf[ks * 2 + 1][0]; av[3] = vf[ks * 2 + 1][1];
        int4v pv;
        pv[0] = (int)pf[ks][0]; pv[1] = (int)pf[ks][1];
        pv[2] = (int)pf[ks][2]; pv[3] = (int)pf[ks][3];
        o[dt] = __builtin_amdgcn_mfma_f32_32x32x16_bf16(
            __builtin_bit_cast(short8, av), __builtin_bit_cast(short8, pv),
            o[dt], 0, 0, 0);
      }
    }
  }

  // epilogue: O[q][d] = o[dt][r]/l ; lane q = l31, d = dt*32+(r&3)+8*(r>>2)+4h
  const float invl = 1.0f / l_r;
  u16* orow = attn + (rowbase + q_glob) * 1024 + hh * 64;
#pragma unroll
  for (int t = 0; t < 2; ++t)
#pragma unroll
    for (int rp = 0; rp < 8; ++rp) {
      const int r0 = rp * 2;
      const u32 w = cvtpk(o[t][r0] * invl, o[t][r0 + 1] * invl);
      const int d = t * 32 + (r0 & 3) + 8 * (r0 >> 2) + 4 * h;
      *(u32*)(orow + d) = w;
    }
}

extern "C" void kernel_launch(void* const* d_in, const int* in_sizes, int n_in,
                              void* d_out, int out_size, void* d_ws, size_t ws_size,
                              hipStream_t stream) {
  const float* x    = (const float*)d_in[0];
  // d_in[1] = mask: known causal (~tril), handled analytically in flash_attn2
  const float* Wqkv = (const float*)d_in[2];
  const float* bqkv = (const float*)d_in[3];
  const float* Wo   = (const float*)d_in[4];
  const float* bo   = (const float*)d_in[5];
  float* out = (float*)d_out;

  const long ML = (long)B_ * L_;  // 8192
  u16* xb    = (u16*)d_ws;                       // [8192][1024]
  u16* wqkvb = xb + ML * D_;                     // [3072][1024]
  u16* wob   = wqkvb + (long)3 * D_ * D_;        // [1024][1024]
  u16* qkv   = wob + (long)D_ * D_;              // [8192][3072]
  u16* attn  = qkv + ML * 3 * D_;                // [8192][1024]

  cvt_bf16<<<dim3((int)(ML * D_ / 1024)), 256, 0, stream>>>(x, xb, (int)(ML * D_));
  cvt_bf16<<<dim3(3 * D_ * D_ / 1024), 256, 0, stream>>>(Wqkv, wqkvb, 3 * D_ * D_);
  cvt_bf16<<<dim3(D_ * D_ / 1024), 256, 0, stream>>>(Wo, wob, D_ * D_);

  gemm_bt<true><<<dim3(3 * D_ / 128, (int)(ML / 128)), 256, 0, stream>>>(
      xb, wqkvb, bqkv, qkv, (int)ML, 3 * D_, D_);

  flash_attn2<<<dim3(16, B_ * H_), 256, 0, stream>>>(qkv, attn);

  gemm_bt<false><<<dim3(D_ / 128, (int)(ML / 128)), 256, 0, stream>>>(
      attn, wob, bo, out, (int)ML, D_, D_);
}

// Round 4
// 192.456 us; speedup vs baseline: 1.8627x; 1.2933x over previous
//
#include <hip/hip_runtime.h>

typedef __attribute__((ext_vector_type(8))) short short8;
typedef __attribute__((ext_vector_type(4))) float f32x4;
typedef __attribute__((ext_vector_type(16))) float f32x16;
typedef __attribute__((ext_vector_type(2))) int int2v;
typedef __attribute__((ext_vector_type(4))) int int4v;
typedef unsigned short u16;
typedef unsigned int u32;

#define B_ 4
#define L_ 2048
#define D_ 1024
#define H_ 16
#define HD_ 64

__device__ __forceinline__ void load_lds16(const void* g, void* l) {
  __builtin_amdgcn_global_load_lds(
      (__attribute__((address_space(1))) unsigned int*)(g),
      (__attribute__((address_space(3))) unsigned int*)(l),
      16, 0, 0);
}

__device__ __forceinline__ u16 f2bf(float f) {
  union { float f; unsigned u; } c; c.f = f;
  unsigned r = c.u + 0x7FFFu + ((c.u >> 16) & 1u);
  return (u16)(r >> 16);
}

__device__ __forceinline__ u32 cvtpk(float a, float b) {
  u32 r; asm("v_cvt_pk_bf16_f32 %0, %1, %2" : "=v"(r) : "v"(a), "v"(b)); return r;
}

__device__ __forceinline__ int2v trread(u32 addr) {
  int2v r; asm volatile("ds_read_b64_tr_b16 %0, %1" : "=v"(r) : "v"(addr)); return r;
}

// ---------------- f32 -> bf16 conversion (4 elems/thread) ----------------
__global__ __launch_bounds__(256) void cvt_bf16(const float* __restrict__ in,
                                                u16* __restrict__ out, int n) {
  int i = (blockIdx.x * 256 + threadIdx.x) * 4;
  if (i >= n) return;
  float4 v = *(const float4*)(in + i);
  u16 o0 = f2bf(v.x), o1 = f2bf(v.y), o2 = f2bf(v.z), o3 = f2bf(v.w);
  u16* p = out + i;
  p[0] = o0; p[1] = o1; p[2] = o2; p[3] = o3;
}

// ---------------- bf16 GEMM, C = A * B^T + bias (m97 structure) ----------
template <bool BF16_OUT>
__global__ __launch_bounds__(256, 2) void gemm_bt(
    const u16* __restrict__ A, const u16* __restrict__ B,
    const float* __restrict__ bias, void* __restrict__ Cout,
    int M, int N, int K) {
  __shared__ u16 Asm[128 * 32];
  __shared__ u16 Bsm[128 * 32];
  const int tid = threadIdx.x;
  const int lane = tid & 63;
  const int wid = tid >> 6;
  const int fr = lane & 15, fq = lane >> 4;
  const int wr = wid >> 1, wc = wid & 1;
  const long m0 = (long)blockIdx.y * 128;
  const long n0 = (long)blockIdx.x * 128;
  const int srow = lane >> 2;
  const int scol = (lane & 3) * 8;

  f32x4 acc[4][4] = {};

  for (int kt = 0; kt < K; kt += 32) {
    __syncthreads();
#pragma unroll
    for (int c = 0; c < 2; ++c) {
      const int sec = wid * 2 + c;
      load_lds16(A + (m0 + sec * 16 + srow) * K + kt + scol,
                 (char*)Asm + sec * 1024);
      load_lds16(B + (n0 + sec * 16 + srow) * K + kt + scol,
                 (char*)Bsm + sec * 1024);
    }
    __syncthreads();
    short8 af[4], bfr[4];
#pragma unroll
    for (int m = 0; m < 4; ++m)
      af[m] = *(const short8*)((const char*)Asm + (wr * 64 + m * 16 + fr) * 64 + fq * 16);
#pragma unroll
    for (int n = 0; n < 4; ++n)
      bfr[n] = *(const short8*)((const char*)Bsm + (wc * 64 + n * 16 + fr) * 64 + fq * 16);
#pragma unroll
    for (int m = 0; m < 4; ++m)
#pragma unroll
      for (int n = 0; n < 4; ++n)
        acc[m][n] = __builtin_amdgcn_mfma_f32_16x16x32_bf16(af[m], bfr[n], acc[m][n], 0, 0, 0);
  }

  float bv[4];
#pragma unroll
  for (int n = 0; n < 4; ++n) bv[n] = bias[n0 + wc * 64 + n * 16 + fr];

#pragma unroll
  for (int m = 0; m < 4; ++m) {
#pragma unroll
    for (int n = 0; n < 4; ++n) {
      const long col = n0 + wc * 64 + n * 16 + fr;
#pragma unroll
      for (int r = 0; r < 4; ++r) {
        const long row = m0 + wr * 64 + m * 16 + fq * 4 + r;
        float v = acc[m][n][r] + bv[n];
        if (BF16_OUT)
          ((u16*)Cout)[row * N + col] = f2bf(v);
        else
          ((float*)Cout)[row * N + col] = v;
      }
    }
  }
}

// ---------------- causal flash attention v3 ------------------------------
// Paired q-tiles (qa = x, qb = 15-x) share the K/V stream -> perfect load
// balance (34 tile-computes per block) + half the staging traffic.
// Double-buffered K/V staged BEFORE compute; single __syncthreads per iter
// drains the prefetch after compute has hidden its latency.
// XCD remap: the 8 q-blocks of one (b,h) land on one XCD's L2.
__global__ __launch_bounds__(256, 2) void flash_attn3(
    const u16* __restrict__ qkv, u16* __restrict__ attn) {
  __shared__ u16 K2[2][64 * 64];  // [row][chunk ^ (row&7)] 16B-chunk swizzled
  __shared__ u16 V2[2][64 * 64];  // subtiled for ds_read_b64_tr_b16

  const int tid = threadIdx.x;
  const int lane = tid & 63;
  const int wid = tid >> 6;
  const int l31 = lane & 31;
  const int h = lane >> 5;

  const int lin = blockIdx.y * 8 + blockIdx.x;        // 0..511
  const int bh = (lin & 7) * 8 + ((lin >> 3) & 7);    // same-bh blocks -> same XCD
  const int x = lin >> 6;                             // 0..7
  const int qa = x, qb = 15 - x;
  const long rowbase = (long)(bh >> 4) * L_;
  const int hh = bh & 15;

  const int wq0A = qa * 128 + wid * 32;
  const int wq0B = qb * 128 + wid * 32;
  const int qgA = wq0A + l31;
  const int qgB = wq0B + l31;

  // Q fragments for both tiles: lane holds Q[qg][ks*16 + h*8 + j]
  short8 qfA[4], qfB[4];
  {
    const u16* qpA = qkv + (rowbase + qgA) * 3072 + hh * 64 + h * 8;
    const u16* qpB = qkv + (rowbase + qgB) * 3072 + hh * 64 + h * 8;
#pragma unroll
    for (int ks = 0; ks < 4; ++ks) {
      qfA[ks] = *(const short8*)(qpA + ks * 16);
      qfB[ks] = *(const short8*)(qpB + ks * 16);
    }
  }

  // staging lane->global mapping (verified in v2)
  int krow[2], kvv[2], dvv[2];
#pragma unroll
  for (int c = 0; c < 2; ++c) {
    const int s = (wid * 2 + c) * 8 + (lane >> 3);
    krow[c] = s;
    kvv[c] = ((s >> 2) << 2) + ((lane >> 1) & 3);
    dvv[c] = ((s & 3) << 4) + ((lane & 1) << 3);
  }
  const int kchunk = ((lane & 7) ^ (lane >> 3)) * 8;

  const u32 Vaddr = (u32)(unsigned long long)(__attribute__((address_space(3))) char*)(void*)&V2[0][0];
  const u32 vb0 = Vaddr + ((lane >> 4) & 1) * 128 + (lane & 15) * 8 + h * 1024;

  f32x16 oA[2] = {}, oB[2] = {};
  float mA = -__builtin_inff(), lA = 0.f;
  float mB = -__builtin_inff(), lB = 0.f;
  const float SC2 = 0.125f * 1.4426950408889634f;  // scale * log2(e)

  auto stage = [&](int kt, int buf) {
    const long ktb = (long)kt * 64;
#pragma unroll
    for (int c = 0; c < 2; ++c) {
      load_lds16(qkv + (rowbase + ktb + krow[c]) * 3072 + 1024 + hh * 64 + kchunk,
                 (char*)&K2[buf][0] + (wid * 2 + c) * 1024);
      load_lds16(qkv + (rowbase + ktb + kvv[c]) * 3072 + 2048 + hh * 64 + dvv[c],
                 (char*)&V2[buf][0] + (wid * 2 + c) * 1024);
    }
  };

  auto computeTile = [&](int ktb, int cur, const short8* qf, int wq0, int qg,
                         f32x16* o, float& m_r, float& l_r) {
    if (ktb > wq0 + 31) return;  // fully masked for this wave
    const char* Kb = (const char*)&K2[cur][0];
    const u32 vbB = vb0 + (u32)cur * 8192;

    // S^T = K * Q^T -> lane q = l31, kv = ktb + t*32 + (r&3)+8*(r>>2)+4h
    f32x16 p[2];
    __builtin_amdgcn_s_setprio(1);
#pragma unroll
    for (int t = 0; t < 2; ++t) {
      f32x16 acc = {};
#pragma unroll
      for (int ks = 0; ks < 4; ++ks) {
        const int row = t * 32 + l31;
        short8 kf = *(const short8*)(Kb + row * 128 + (((ks * 2 + h) ^ (row & 7)) * 16));
        acc = __builtin_amdgcn_mfma_f32_32x32x16_bf16(kf, qf[ks], acc, 0, 0, 0);
      }
      p[t] = acc;
    }
    __builtin_amdgcn_s_setprio(0);

    // causal mask when the tile can reach past the wave's FIRST q row
    if (ktb + 63 > wq0) {
#pragma unroll
      for (int t = 0; t < 2; ++t)
#pragma unroll
        for (int r = 0; r < 16; ++r) {
          const int kvg = ktb + t * 32 + (r & 3) + 8 * (r >> 2) + 4 * h;
          p[t][r] = (kvg > qg) ? -__builtin_inff() : p[t][r];
        }
    }

    // row max
    float a[16];
#pragma unroll
    for (int r = 0; r < 16; ++r) a[r] = fmaxf(p[0][r], p[1][r]);
#pragma unroll
    for (int s = 8; s > 0; s >>= 1)
#pragma unroll
      for (int r = 0; r < s; ++r) a[r] = fmaxf(a[r], a[r + s]);
    const float mt = fmaxf(a[0], __shfl_xor(a[0], 32));

    const float m_new = fmaxf(m_r, mt);
    const float alpha = __builtin_exp2f((m_r - m_new) * SC2);
    const float msc = m_new * SC2;
#pragma unroll
    for (int t = 0; t < 2; ++t)
#pragma unroll
      for (int r = 0; r < 16; ++r)
        p[t][r] = __builtin_exp2f(fmaf(p[t][r], SC2, -msc));

    // row sum
    float b2[16];
#pragma unroll
    for (int r = 0; r < 16; ++r) b2[r] = p[0][r] + p[1][r];
#pragma unroll
    for (int s = 8; s > 0; s >>= 1)
#pragma unroll
      for (int r = 0; r < s; ++r) b2[r] += b2[r + s];
    const float rs = b2[0] + __shfl_xor(b2[0], 32);

    l_r = alpha * l_r + rs;
    m_r = m_new;
#pragma unroll
    for (int t = 0; t < 2; ++t)
#pragma unroll
      for (int r = 0; r < 16; ++r) o[t][r] *= alpha;

    // pack P^T fragments
    u32 pf[4][4];
#pragma unroll
    for (int t = 0; t < 2; ++t)
#pragma unroll
      for (int ksl = 0; ksl < 2; ++ksl) {
        const u32 x0 = cvtpk(p[t][8 * ksl + 0], p[t][8 * ksl + 1]);
        const u32 x1 = cvtpk(p[t][8 * ksl + 2], p[t][8 * ksl + 3]);
        const u32 y0 = cvtpk(p[t][8 * ksl + 4], p[t][8 * ksl + 5]);
        const u32 y1 = cvtpk(p[t][8 * ksl + 6], p[t][8 * ksl + 7]);
        const u32 r0 = (u32)__shfl_xor((int)(h ? x0 : y0), 32);
        const u32 r1 = (u32)__shfl_xor((int)(h ? x1 : y1), 32);
        const int ks = t * 2 + ksl;
        pf[ks][0] = h ? r0 : x0;
        pf[ks][1] = h ? r1 : x1;
        pf[ks][2] = h ? y0 : r0;
        pf[ks][3] = h ? y1 : r1;
      }

    // O^T += V^T * P^T
#pragma unroll
    for (int dt = 0; dt < 2; ++dt) {
      int2v vf[8];
#pragma unroll
      for (int ks = 0; ks < 4; ++ks) {
        vf[ks * 2 + 0] = trread(vbB + dt * 256 + ks * 2048);
        vf[ks * 2 + 1] = trread(vbB + dt * 256 + ks * 2048 + 512);
      }
      asm volatile("s_waitcnt lgkmcnt(0)" ::: "memory");
      __builtin_amdgcn_sched_barrier(0);
      __builtin_amdgcn_s_setprio(1);
#pragma unroll
      for (int ks = 0; ks < 4; ++ks) {
        int4v av;
        av[0] = vf[ks * 2][0]; av[1] = vf[ks * 2][1];
        av[2] = vf[ks * 2 + 1][0]; av[3] = vf[ks * 2 + 1][1];
        int4v pv;
        pv[0] = (int)pf[ks][0]; pv[1] = (int)pf[ks][1];
        pv[2] = (int)pf[ks][2]; pv[3] = (int)pf[ks][3];
        o[dt] = __builtin_amdgcn_mfma_f32_32x32x16_bf16(
            __builtin_bit_cast(short8, av), __builtin_bit_cast(short8, pv),
            o[dt], 0, 0, 0);
      }
      __builtin_amdgcn_s_setprio(0);
    }
  };

  stage(0, 0);
  __syncthreads();
  int cur = 0;
  const int kmB = 2 * qb + 1, kmA = 2 * qa + 1;
  for (int kt = 0; kt <= kmB; ++kt) {
    if (kt < kmB) stage(kt + 1, cur ^ 1);  // prefetch overlaps both computes
    computeTile(kt * 64, cur, qfB, wq0B, qgB, oB, mB, lB);
    if (kt <= kmA) computeTile(kt * 64, cur, qfA, wq0A, qgA, oA, mA, lA);
    __syncthreads();  // drains prefetch (latency already hidden) + buf reuse fence
    cur ^= 1;
  }

  // epilogue: O[q][d] = o[dt][r]/l ; d = dt*32+(r&3)+8*(r>>2)+4h
  {
    const float invl = 1.0f / lB;
    u16* orow = attn + (rowbase + qgB) * 1024 + hh * 64;
#pragma unroll
    for (int t = 0; t < 2; ++t)
#pragma unroll
      for (int rp = 0; rp < 8; ++rp) {
        const int r0 = rp * 2;
        const u32 w = cvtpk(oB[t][r0] * invl, oB[t][r0 + 1] * invl);
        const int d = t * 32 + (r0 & 3) + 8 * (r0 >> 2) + 4 * h;
        *(u32*)(orow + d) = w;
      }
  }
  {
    const float invl = 1.0f / lA;
    u16* orow = attn + (rowbase + qgA) * 1024 + hh * 64;
#pragma unroll
    for (int t = 0; t < 2; ++t)
#pragma unroll
      for (int rp = 0; rp < 8; ++rp) {
        const int r0 = rp * 2;
        const u32 w = cvtpk(oA[t][r0] * invl, oA[t][r0 + 1] * invl);
        const int d = t * 32 + (r0 & 3) + 8 * (r0 >> 2) + 4 * h;
        *(u32*)(orow + d) = w;
      }
  }
}

extern "C" void kernel_launch(void* const* d_in, const int* in_sizes, int n_in,
                              void* d_out, int out_size, void* d_ws, size_t ws_size,
                              hipStream_t stream) {
  const float* x    = (const float*)d_in[0];
  // d_in[1] = mask: known causal (~tril), handled analytically in flash_attn3
  const float* Wqkv = (const float*)d_in[2];
  const float* bqkv = (const float*)d_in[3];
  const float* Wo   = (const float*)d_in[4];
  const float* bo   = (const float*)d_in[5];
  float* out = (float*)d_out;

  const long ML = (long)B_ * L_;  // 8192
  u16* xb    = (u16*)d_ws;                       // [8192][1024]
  u16* wqkvb = xb + ML * D_;                     // [3072][1024]
  u16* wob   = wqkvb + (long)3 * D_ * D_;        // [1024][1024]
  u16* qkv   = wob + (long)D_ * D_;              // [8192][3072]
  u16* attn  = qkv + ML * 3 * D_;                // [8192][1024]

  cvt_bf16<<<dim3((int)(ML * D_ / 1024)), 256, 0, stream>>>(x, xb, (int)(ML * D_));
  cvt_bf16<<<dim3(3 * D_ * D_ / 1024), 256, 0, stream>>>(Wqkv, wqkvb, 3 * D_ * D_);
  cvt_bf16<<<dim3(D_ * D_ / 1024), 256, 0, stream>>>(Wo, wob, D_ * D_);

  gemm_bt<true><<<dim3(3 * D_ / 128, (int)(ML / 128)), 256, 0, stream>>>(
      xb, wqkvb, bqkv, qkv, (int)ML, 3 * D_, D_);

  flash_attn3<<<dim3(8, B_ * H_), 256, 0, stream>>>(qkv, attn);

  gemm_bt<false><<<dim3(D_ / 128, (int)(ML / 128)), 256, 0, stream>>>(
      attn, wob, bo, out, (int)ML, D_, D_);
}